// Round 1
// baseline (376.660 us; speedup 1.0000x reference)
//
#include <hip/hip_runtime.h>

typedef __attribute__((ext_vector_type(8))) short short8;
typedef __attribute__((ext_vector_type(4))) float f32x4;

// Problem dims
#define BDIM 4096
#define INDIM 1024
#define HDIM 2048
#define KDIM 3072   // IN + H
#define NDIM 8192   // 4*H
#define OUT_HALF 8388608  // 4096*2048

__device__ __forceinline__ unsigned short f2bf(float f) {
  unsigned u = __float_as_uint(f);
  u += 0x7FFFu + ((u >> 16) & 1u);
  return (unsigned short)(u >> 16);
}

__device__ __forceinline__ float sigmoidf_(float x) {
  return 1.0f / (1.0f + __expf(-x));
}

// Pack A = [x | h] as bf16, row-major [4096][3072]
__global__ __launch_bounds__(256) void pack_a(const float* __restrict__ x,
                                              const float* __restrict__ hh,
                                              unsigned short* __restrict__ A) {
  int idx = blockIdx.x * 256 + threadIdx.x;      // 1,572,864 chunks of 8
  int m = idx / 384;
  int k0 = (idx - m * 384) * 8;
  const float* src = (k0 < INDIM) ? (x + (size_t)m * INDIM + k0)
                                  : (hh + (size_t)m * HDIM + (k0 - INDIM));
  float4 lo = ((const float4*)src)[0];
  float4 hi = ((const float4*)src)[1];
  union { unsigned short us[8]; uint4 v; } o;
  o.us[0] = f2bf(lo.x); o.us[1] = f2bf(lo.y); o.us[2] = f2bf(lo.z); o.us[3] = f2bf(lo.w);
  o.us[4] = f2bf(hi.x); o.us[5] = f2bf(hi.y); o.us[6] = f2bf(hi.z); o.us[7] = f2bf(hi.w);
  *(uint4*)(A + (size_t)m * KDIM + k0) = o.v;
}

// Pack W' (gate-interleaved rows) as bf16 [8192][3072]; W'[4*j+g] = [w_ih|w_hh][g*2048+j]
// Also bias[n'] = b_ih[n] + b_hh[n]
__global__ __launch_bounds__(256) void pack_w(const float* __restrict__ w_ih,
                                              const float* __restrict__ w_hh,
                                              const float* __restrict__ b_ih,
                                              const float* __restrict__ b_hh,
                                              unsigned short* __restrict__ W,
                                              float* __restrict__ bias) {
  int idx = blockIdx.x * 256 + threadIdx.x;      // 3,145,728 chunks of 8
  int np = idx / 384;
  int rem = idx - np * 384;
  int k0 = rem * 8;
  int j = np >> 2;
  int g = np & 3;
  int n = g * HDIM + j;
  const float* src = (k0 < INDIM) ? (w_ih + (size_t)n * INDIM + k0)
                                  : (w_hh + (size_t)n * HDIM + (k0 - INDIM));
  float4 lo = ((const float4*)src)[0];
  float4 hi = ((const float4*)src)[1];
  union { unsigned short us[8]; uint4 v; } o;
  o.us[0] = f2bf(lo.x); o.us[1] = f2bf(lo.y); o.us[2] = f2bf(lo.z); o.us[3] = f2bf(lo.w);
  o.us[4] = f2bf(hi.x); o.us[5] = f2bf(hi.y); o.us[6] = f2bf(hi.z); o.us[7] = f2bf(hi.w);
  *(uint4*)(W + (size_t)np * KDIM + k0) = o.v;
  if (rem == 0) bias[np] = b_ih[n] + b_hh[n];
}

__device__ __forceinline__ void gload_lds16(const void* g, void* l) {
  __builtin_amdgcn_global_load_lds(
      (const __attribute__((address_space(1))) void*)g,
      (__attribute__((address_space(3))) void*)l, 16, 0, 0);
}

// Fused GEMM + LSTM epilogue.
// gates[m][n'] = sum_k A[m][k]*W'[n'][k]  (+bias in epilogue)
// 128x128 tile, BK=32, 4 waves (2x2 of 64x64), mfma_f32_16x16x32_bf16.
__global__ __launch_bounds__(256) void lstm_gemm(
    const unsigned short* __restrict__ A,
    const unsigned short* __restrict__ W,
    const float* __restrict__ bias,
    const float* __restrict__ c,
    float* __restrict__ out) {
  __shared__ union __align__(16) {
    unsigned short ab[8192];  // As[128][32] at 0, Bs[128][32] at 4096
    float ep[4096];           // epilogue bounce: [4 waves][16 rows][64 cols]
  } sm;

  const int tid = threadIdx.x;
  const int lane = tid & 63;
  const int wid = tid >> 6;

  // XCD-bijective swizzle (2048 % 8 == 0)
  int bid = blockIdx.x;
  int swz = (bid & 7) * 256 + (bid >> 3);
  const int tn = swz & 63;   // 64 n-tiles
  const int tm = swz >> 6;   // 32 m-tiles

  // Staging slots: slot s covers LDS bytes [16s,16s+16) of an 8KB tile region.
  // wave w issue q stages slots [ (w*2+q)*64, +64 ), lane -> base + lane*16.
  const int s0 = wid * 128 + lane;
  const int s1 = s0 + 64;
  const int rA0 = s0 >> 2, cA0 = (s0 & 3) * 8;
  const int rA1 = s1 >> 2, cA1 = (s1 & 3) * 8;

  const unsigned short* Abase = A + (size_t)tm * 128 * KDIM;
  const unsigned short* Wbase = W + (size_t)tn * 128 * KDIM;
  const unsigned short* ga0 = Abase + (size_t)rA0 * KDIM + cA0;
  const unsigned short* ga1 = Abase + (size_t)rA1 * KDIM + cA1;
  const unsigned short* gb0 = Wbase + (size_t)rA0 * KDIM + cA0;
  const unsigned short* gb1 = Wbase + (size_t)rA1 * KDIM + cA1;

  unsigned short* ldsA0 = sm.ab + (wid * 2 + 0) * 512;
  unsigned short* ldsA1 = sm.ab + (wid * 2 + 1) * 512;
  unsigned short* ldsB0 = sm.ab + 4096 + (wid * 2 + 0) * 512;
  unsigned short* ldsB1 = sm.ab + 4096 + (wid * 2 + 1) * 512;

  f32x4 acc[4][4] = {};

  const int fr = lane & 15;   // frag row(A)/col(B)
  const int fq = lane >> 4;   // k-quad
  const int wr = wid >> 1;    // wave row (0..1)
  const int wc = wid & 1;     // wave col (0..1)

  for (int kt = 0; kt < KDIM / 32; ++kt) {
    __syncthreads();
    gload_lds16(ga0, ldsA0);
    gload_lds16(ga1, ldsA1);
    gload_lds16(gb0, ldsB0);
    gload_lds16(gb1, ldsB1);
    ga0 += 32; ga1 += 32; gb0 += 32; gb1 += 32;
    __syncthreads();

    short8 af[4], bfr[4];
#pragma unroll
    for (int mi = 0; mi < 4; ++mi)
      af[mi] = *(const short8*)(sm.ab + (wr * 64 + mi * 16 + fr) * 32 + fq * 8);
#pragma unroll
    for (int ni = 0; ni < 4; ++ni)
      bfr[ni] = *(const short8*)(sm.ab + 4096 + (wc * 64 + ni * 16 + fr) * 32 + fq * 8);
#pragma unroll
    for (int mi = 0; mi < 4; ++mi)
#pragma unroll
      for (int ni = 0; ni < 4; ++ni)
        acc[mi][ni] = __builtin_amdgcn_mfma_f32_16x16x32_bf16(af[mi], bfr[ni], acc[mi][ni], 0, 0, 0);
  }

  // ---- fused LSTM epilogue ----
  // Wave owns 64x64 gates: rows tm*128+wr*64+[0,64), cols tn*128+wc*64+[0,64).
  // Cols are 16 j's * 4 gates (f,i,ic,o). Bounce via LDS one mi-slice at a time.
  const int jw = fr;                       // j within wave's 16
  const int jg = tn * 32 + wc * 16 + jw;   // global j in [0,2048)
  const f32x4 bi = *(const f32x4*)(bias + tn * 128 + wc * 64 + jw * 4);
  float* ep = sm.ep + wid * 1024;

#pragma unroll
  for (int mi = 0; mi < 4; ++mi) {
    __syncthreads();
#pragma unroll
    for (int ni = 0; ni < 4; ++ni)
#pragma unroll
      for (int r = 0; r < 4; ++r)
        ep[(fq * 4 + r) * 64 + ni * 16 + fr] = acc[mi][ni][r];
    __syncthreads();
#pragma unroll
    for (int t = 0; t < 4; ++t) {
      const int row = fq + t * 4;          // 0..15
      f32x4 g4 = *(const f32x4*)(ep + row * 64 + jw * 4);
      const float f_in = g4[0] + bi[0];
      const float i_in = g4[1] + bi[1];
      const float ic_in = g4[2] + bi[2];
      const float o_in = g4[3] + bi[3];
      const float ft = sigmoidf_(f_in);
      const float it = sigmoidf_(i_in);
      const float ics = __sinf(ic_in);
      const int mg = tm * 128 + wr * 64 + mi * 16 + row;
      const float cv = c[(size_t)mg * HDIM + jg];
      const float ct = cv * ft + ics * it;
      const float ot = sigmoidf_(o_in);
      const float ht = ot * __sinf(ct);
      out[(size_t)mg * HDIM + jg] = ht;
      out[OUT_HALF + (size_t)mg * HDIM + jg] = ct;
    }
  }
}

extern "C" void kernel_launch(void* const* d_in, const int* in_sizes, int n_in,
                              void* d_out, int out_size, void* d_ws, size_t ws_size,
                              hipStream_t stream) {
  const float* x    = (const float*)d_in[0];
  const float* h    = (const float*)d_in[1];
  const float* c    = (const float*)d_in[2];
  const float* w_ih = (const float*)d_in[3];
  const float* w_hh = (const float*)d_in[4];
  const float* b_ih = (const float*)d_in[5];
  const float* b_hh = (const float*)d_in[6];
  float* out = (float*)d_out;

  char* ws = (char*)d_ws;
  unsigned short* Abf = (unsigned short*)ws;                       // 25,165,824 B
  unsigned short* Wbf = (unsigned short*)(ws + 25165824);          // 50,331,648 B
  float* bias = (float*)(ws + 25165824 + 50331648);                // 32,768 B

  pack_a<<<6144, 256, 0, stream>>>(x, h, Abf);
  pack_w<<<12288, 256, 0, stream>>>(w_ih, w_hh, b_ih, b_hh, Wbf, bias);
  lstm_gemm<<<2048, 256, 0, stream>>>(Abf, Wbf, bias, c, out);
}

// Round 2
// 290.094 us; speedup vs baseline: 1.2984x; 1.2984x over previous
//
#include <hip/hip_runtime.h>

typedef __attribute__((ext_vector_type(8))) short short8;
typedef __attribute__((ext_vector_type(4))) float f32x4;

// Problem dims
#define BDIM 4096
#define INDIM 1024
#define HDIM 2048
#define KDIM 3072   // IN + H
#define NDIM 8192   // 4*H
#define OUT_HALF 8388608  // 4096*2048
#define NT 96       // K-tiles of 32

__device__ __forceinline__ unsigned short f2bf(float f) {
  unsigned u = __float_as_uint(f);
  u += 0x7FFFu + ((u >> 16) & 1u);
  return (unsigned short)(u >> 16);
}

__device__ __forceinline__ float sigmoidf_(float x) {
  return 1.0f / (1.0f + __expf(-x));
}

// Pack A = [x | h] as bf16, row-major [4096][3072]
__global__ __launch_bounds__(256) void pack_a(const float* __restrict__ x,
                                              const float* __restrict__ hh,
                                              unsigned short* __restrict__ A) {
  int idx = blockIdx.x * 256 + threadIdx.x;      // 1,572,864 chunks of 8
  int m = idx / 384;
  int k0 = (idx - m * 384) * 8;
  const float* src = (k0 < INDIM) ? (x + (size_t)m * INDIM + k0)
                                  : (hh + (size_t)m * HDIM + (k0 - INDIM));
  float4 lo = ((const float4*)src)[0];
  float4 hi = ((const float4*)src)[1];
  union { unsigned short us[8]; uint4 v; } o;
  o.us[0] = f2bf(lo.x); o.us[1] = f2bf(lo.y); o.us[2] = f2bf(lo.z); o.us[3] = f2bf(lo.w);
  o.us[4] = f2bf(hi.x); o.us[5] = f2bf(hi.y); o.us[6] = f2bf(hi.z); o.us[7] = f2bf(hi.w);
  *(uint4*)(A + (size_t)m * KDIM + k0) = o.v;
}

// Pack W' (gate-interleaved rows) as bf16 [8192][3072]; W'[4*j+g] = [w_ih|w_hh][g*2048+j]
// Also bias[n'] = b_ih[n] + b_hh[n]
__global__ __launch_bounds__(256) void pack_w(const float* __restrict__ w_ih,
                                              const float* __restrict__ w_hh,
                                              const float* __restrict__ b_ih,
                                              const float* __restrict__ b_hh,
                                              unsigned short* __restrict__ W,
                                              float* __restrict__ bias) {
  int idx = blockIdx.x * 256 + threadIdx.x;      // 3,145,728 chunks of 8
  int np = idx / 384;
  int rem = idx - np * 384;
  int k0 = rem * 8;
  int j = np >> 2;
  int g = np & 3;
  int n = g * HDIM + j;
  const float* src = (k0 < INDIM) ? (w_ih + (size_t)n * INDIM + k0)
                                  : (w_hh + (size_t)n * HDIM + (k0 - INDIM));
  float4 lo = ((const float4*)src)[0];
  float4 hi = ((const float4*)src)[1];
  union { unsigned short us[8]; uint4 v; } o;
  o.us[0] = f2bf(lo.x); o.us[1] = f2bf(lo.y); o.us[2] = f2bf(lo.z); o.us[3] = f2bf(lo.w);
  o.us[4] = f2bf(hi.x); o.us[5] = f2bf(hi.y); o.us[6] = f2bf(hi.z); o.us[7] = f2bf(hi.w);
  *(uint4*)(W + (size_t)np * KDIM + k0) = o.v;
  if (rem == 0) bias[np] = b_ih[n] + b_hh[n];
}

__device__ __forceinline__ void gload_lds16(const void* g, void* l) {
  __builtin_amdgcn_global_load_lds(
      (const __attribute__((address_space(1))) void*)g,
      (__attribute__((address_space(3))) void*)l, 16, 0, 0);
}

#define SCHED0 __builtin_amdgcn_sched_barrier(0)

// Fused GEMM + LSTM epilogue.
// 128x128 tile, BK=32, 4 waves, mfma_f32_16x16x32_bf16.
// Double-buffered LDS, raw s_barrier + counted vmcnt (loads span barriers).
__global__ __launch_bounds__(256) void lstm_gemm(
    const unsigned short* __restrict__ A,
    const unsigned short* __restrict__ W,
    const float* __restrict__ bias,
    const float* __restrict__ c,
    float* __restrict__ out) {
  // buf k at smem + k*8192 shorts (16KB each): A [128][32] at +0, B at +4096.
  // Epilogue reuses buf0 region (final tile reads buf1) as float[4096].
  __shared__ __align__(16) unsigned short smem[16384];

  const int tid = threadIdx.x;
  const int lane = tid & 63;
  const int wid = tid >> 6;

  // XCD swizzle: XCD x owns tm slab x*4..x*4+3 (A slab ~3MB, L2-resident),
  // sweeps tn with tm_local fastest. Bijective over 2048 blocks.
  const int bid = blockIdx.x;
  const int tm = (bid & 7) * 4 + ((bid >> 3) & 3);   // 0..31
  const int tn = bid >> 5;                           // 0..63

  // Staging: wave w issue q covers LDS slots [(w*2+q)*64, +64), lane l -> +l*16B.
  const int rq = lane >> 2;        // row within 16-row issue group
  const int cq = (lane & 3) * 8;   // col offset (shorts)
  const unsigned short* gA0 = A + (size_t)(tm * 128 + wid * 32 + rq) * KDIM + cq;
  const unsigned short* gA1 = gA0 + (size_t)16 * KDIM;
  const unsigned short* gB0 = W + (size_t)(tn * 128 + wid * 32 + rq) * KDIM + cq;
  const unsigned short* gB1 = gB0 + (size_t)16 * KDIM;

  const int sA0 = (wid * 2 + 0) * 512;
  const int sA1 = (wid * 2 + 1) * 512;
  const int sB0 = 4096 + (wid * 2 + 0) * 512;
  const int sB1 = 4096 + (wid * 2 + 1) * 512;
  unsigned short* l0 = smem;
  unsigned short* l1 = smem + 8192;

  // Prologue: stage tile0 -> buf0, tile1 -> buf1 (8 gloads in flight)
  gload_lds16(gA0, l0 + sA0); gload_lds16(gA1, l0 + sA1);
  gload_lds16(gB0, l0 + sB0); gload_lds16(gB1, l0 + sB1);
  gload_lds16(gA0 + 32, l1 + sA0); gload_lds16(gA1 + 32, l1 + sA1);
  gload_lds16(gB0 + 32, l1 + sB0); gload_lds16(gB1 + 32, l1 + sB1);
  gA0 += 64; gA1 += 64; gB0 += 64; gB1 += 64;

  asm volatile("s_waitcnt vmcnt(4)" ::: "memory"); SCHED0;   // tile0 landed
  __builtin_amdgcn_s_barrier(); SCHED0;

  f32x4 acc[4][4] = {};
  const int fr = lane & 15;
  const int fq = lane >> 4;
  const int wr = wid >> 1;
  const int wc = wid & 1;

  for (int t = 0; t < NT; ++t) {
    const unsigned short* As = smem + (t & 1) * 8192;
    const unsigned short* Bs = As + 4096;
    short8 af[4], bfr[4];
#pragma unroll
    for (int mi = 0; mi < 4; ++mi)
      af[mi] = *(const short8*)(As + (wr * 64 + mi * 16 + fr) * 32 + fq * 8);
#pragma unroll
    for (int ni = 0; ni < 4; ++ni)
      bfr[ni] = *(const short8*)(Bs + (wc * 64 + ni * 16 + fr) * 32 + fq * 8);
    // all reads of buf[t&1] retired -> safe to overwrite after barrier
    asm volatile("s_waitcnt lgkmcnt(0)" ::: "memory"); SCHED0;
    __builtin_amdgcn_s_barrier(); SCHED0;

    if (t + 2 < NT) {  // stage tile t+2 into buf[t&1]
      unsigned short* lb = smem + (t & 1) * 8192;
      gload_lds16(gA0, lb + sA0); gload_lds16(gA1, lb + sA1);
      gload_lds16(gB0, lb + sB0); gload_lds16(gB1, lb + sB1);
      gA0 += 32; gA1 += 32; gB0 += 32; gB1 += 32;
    }

#pragma unroll
    for (int mi = 0; mi < 4; ++mi)
#pragma unroll
      for (int ni = 0; ni < 4; ++ni)
        acc[mi][ni] = __builtin_amdgcn_mfma_f32_16x16x32_bf16(af[mi], bfr[ni], acc[mi][ni], 0, 0, 0);

    // tile t+1 must be landed before next iteration's ds_reads;
    // keep tile t+2's 4 loads in flight (never drain to 0 mid-loop).
    if (t + 2 < NT) { asm volatile("s_waitcnt vmcnt(4)" ::: "memory"); }
    else            { asm volatile("s_waitcnt vmcnt(0)" ::: "memory"); }
    SCHED0;
    __builtin_amdgcn_s_barrier(); SCHED0;
  }

  // ---- fused LSTM epilogue ----
  // Wave owns 64x64 gates. ep regions are wave-private (buf0; final tile read buf1)
  // -> no cross-wave barriers needed. Within-wave write->read ordered by lgkmcnt.
  const int jw = fr;                       // j within wave's 16
  const int jg = tn * 32 + wc * 16 + jw;   // global j in [0,2048)
  const f32x4 bi = *(const f32x4*)(bias + tn * 128 + wc * 64 + jw * 4);
  float* ep = ((float*)smem) + wid * 1024;

#pragma unroll
  for (int mi = 0; mi < 4; ++mi) {
#pragma unroll
    for (int ni = 0; ni < 4; ++ni)
#pragma unroll
      for (int r = 0; r < 4; ++r)
        ep[(fq * 4 + r) * 64 + ni * 16 + fr] = acc[mi][ni][r];
    asm volatile("s_waitcnt lgkmcnt(0)" ::: "memory");
#pragma unroll
    for (int t4 = 0; t4 < 4; ++t4) {
      const int row = fq + t4 * 4;         // 0..15
      f32x4 g4 = *(const f32x4*)(ep + row * 64 + jw * 4);
      const float f_in = g4[0] + bi[0];
      const float i_in = g4[1] + bi[1];
      const float ic_in = g4[2] + bi[2];
      const float o_in = g4[3] + bi[3];
      const float ft = sigmoidf_(f_in);
      const float it = sigmoidf_(i_in);
      const float ics = __sinf(ic_in);
      const int mg = tm * 128 + wr * 64 + mi * 16 + row;
      const float cv = c[(size_t)mg * HDIM + jg];
      const float ct = cv * ft + ics * it;
      const float ot = sigmoidf_(o_in);
      const float ht = ot * __sinf(ct);
      out[(size_t)mg * HDIM + jg] = ht;
      out[OUT_HALF + (size_t)mg * HDIM + jg] = ct;
    }
  }
}

extern "C" void kernel_launch(void* const* d_in, const int* in_sizes, int n_in,
                              void* d_out, int out_size, void* d_ws, size_t ws_size,
                              hipStream_t stream) {
  const float* x    = (const float*)d_in[0];
  const float* h    = (const float*)d_in[1];
  const float* c    = (const float*)d_in[2];
  const float* w_ih = (const float*)d_in[3];
  const float* w_hh = (const float*)d_in[4];
  const float* b_ih = (const float*)d_in[5];
  const float* b_hh = (const float*)d_in[6];
  float* out = (float*)d_out;

  char* ws = (char*)d_ws;
  unsigned short* Abf = (unsigned short*)ws;                       // 25,165,824 B
  unsigned short* Wbf = (unsigned short*)(ws + 25165824);          // 50,331,648 B
  float* bias = (float*)(ws + 25165824 + 50331648);                // 32,768 B

  pack_a<<<6144, 256, 0, stream>>>(x, h, Abf);
  pack_w<<<12288, 256, 0, stream>>>(w_ih, w_hh, b_ih, b_hh, Wbf, bias);
  lstm_gemm<<<2048, 256, 0, stream>>>(Abf, Wbf, bias, c, out);
}

// Round 3
// 233.453 us; speedup vs baseline: 1.6134x; 1.2426x over previous
//
#include <hip/hip_runtime.h>

typedef __attribute__((ext_vector_type(8))) short short8;
typedef __attribute__((ext_vector_type(4))) float f32x4;

// Problem dims
#define BDIM 4096
#define INDIM 1024
#define HDIM 2048
#define KDIM 3072   // IN + H
#define NDIM 8192   // 4*H
#define OUT_HALF 8388608  // 4096*2048
#define NKT 96      // K-tiles of 32

__device__ __forceinline__ unsigned short f2bf(float f) {
  unsigned u = __float_as_uint(f);
  u += 0x7FFFu + ((u >> 16) & 1u);
  return (unsigned short)(u >> 16);
}

__device__ __forceinline__ float sigmoidf_(float x) {
  return 1.0f / (1.0f + __expf(-x));
}

// Pack A = [x | h] as bf16, row-major [4096][3072]
__global__ __launch_bounds__(256) void pack_a(const float* __restrict__ x,
                                              const float* __restrict__ hh,
                                              unsigned short* __restrict__ A) {
  int idx = blockIdx.x * 256 + threadIdx.x;
  int m = idx / 384;
  int k0 = (idx - m * 384) * 8;
  const float* src = (k0 < INDIM) ? (x + (size_t)m * INDIM + k0)
                                  : (hh + (size_t)m * HDIM + (k0 - INDIM));
  float4 lo = ((const float4*)src)[0];
  float4 hi = ((const float4*)src)[1];
  union { unsigned short us[8]; uint4 v; } o;
  o.us[0] = f2bf(lo.x); o.us[1] = f2bf(lo.y); o.us[2] = f2bf(lo.z); o.us[3] = f2bf(lo.w);
  o.us[4] = f2bf(hi.x); o.us[5] = f2bf(hi.y); o.us[6] = f2bf(hi.z); o.us[7] = f2bf(hi.w);
  *(uint4*)(A + (size_t)m * KDIM + k0) = o.v;
}

// Pack W' (gate-interleaved rows) as bf16 [8192][3072]; W'[4*j+g] = [w_ih|w_hh][g*2048+j]
__global__ __launch_bounds__(256) void pack_w(const float* __restrict__ w_ih,
                                              const float* __restrict__ w_hh,
                                              const float* __restrict__ b_ih,
                                              const float* __restrict__ b_hh,
                                              unsigned short* __restrict__ W,
                                              float* __restrict__ bias) {
  int idx = blockIdx.x * 256 + threadIdx.x;
  int np = idx / 384;
  int rem = idx - np * 384;
  int k0 = rem * 8;
  int j = np >> 2;
  int g = np & 3;
  int n = g * HDIM + j;
  const float* src = (k0 < INDIM) ? (w_ih + (size_t)n * INDIM + k0)
                                  : (w_hh + (size_t)n * HDIM + (k0 - INDIM));
  float4 lo = ((const float4*)src)[0];
  float4 hi = ((const float4*)src)[1];
  union { unsigned short us[8]; uint4 v; } o;
  o.us[0] = f2bf(lo.x); o.us[1] = f2bf(lo.y); o.us[2] = f2bf(lo.z); o.us[3] = f2bf(lo.w);
  o.us[4] = f2bf(hi.x); o.us[5] = f2bf(hi.y); o.us[6] = f2bf(hi.z); o.us[7] = f2bf(hi.w);
  *(uint4*)(W + (size_t)np * KDIM + k0) = o.v;
  if (rem == 0) bias[np] = b_ih[n] + b_hh[n];
}

__device__ __forceinline__ void gload_lds16(const void* g, void* l) {
  __builtin_amdgcn_global_load_lds(
      (const __attribute__((address_space(1))) void*)g,
      (__attribute__((address_space(3))) void*)l, 16, 0, 0);
}

// 256x256 tile, BK=32, 8 waves (2Mx4N), 4-deep LDS ring (4 x 32KiB),
// row-pair XOR swizzle (T2), counted vmcnt (T4), setprio (T5).
// Buffer b at smem + b*32768: A region [256][32]bf16 swizzled at +0 (16KiB),
// B region at +16384. Swizzle: within each 128B row-pair (row2 = row>>1),
// 16B chunk_phys = chunk_log ^ (row2&7), chunk_log = (row&1)*4 + col/8.
__global__ __launch_bounds__(512, 2) void lstm_gemm(
    const unsigned short* __restrict__ A,
    const unsigned short* __restrict__ W,
    const float* __restrict__ bias,
    const float* __restrict__ c,
    float* __restrict__ out) {
  extern __shared__ char smem[];  // 131072 bytes

  const int tid = threadIdx.x;
  const int lane = tid & 63;
  const int wid = tid >> 6;

  // XCD swizzle: xcd owns 2 tm slabs (3MB A, L2-resident); tn sweeps slowest
  // so the first 256 blocks share W cols 0..4095 (L3-resident). Bijective.
  const int bid = blockIdx.x;              // 512 blocks
  const int local = bid >> 3;              // 0..63
  const int tm = (bid & 7) * 2 + (local & 1);   // 0..15
  const int tn = local >> 1;                    // 0..31

  // ---- staging source decode (inverse swizzle, rule #21) ----
  // Round q of A: LDS phys P = q*8192 + wid*1024 + lane*16 (within A region).
  int rowA0, clA0, rowA1, clA1, rowB0, clB0, rowB1, clB1;
  {
    int P0 = wid * 1024 + lane * 16;
    int P1 = 8192 + wid * 1024 + lane * 16;
    int r2, cp, cg;
    r2 = P0 >> 7; cp = (P0 >> 4) & 7; cg = cp ^ (r2 & 7);
    rowA0 = r2 * 2 + (cg >> 2); clA0 = cg & 3;
    r2 = P1 >> 7; cp = (P1 >> 4) & 7; cg = cp ^ (r2 & 7);
    rowA1 = r2 * 2 + (cg >> 2); clA1 = cg & 3;
    rowB0 = rowA0; clB0 = clA0;   // same P formula within B region
    rowB1 = rowA1; clB1 = clA1;
  }
  const unsigned short* srcA0 = A + (size_t)(tm * 256 + rowA0) * KDIM + clA0 * 8;
  const unsigned short* srcA1 = A + (size_t)(tm * 256 + rowA1) * KDIM + clA1 * 8;
  const unsigned short* srcB0 = W + (size_t)(tn * 256 + rowB0) * KDIM + clB0 * 8;
  const unsigned short* srcB1 = W + (size_t)(tn * 256 + rowB1) * KDIM + clB1 * 8;
  const int ldA0 = wid * 1024;
  const int ldA1 = 8192 + wid * 1024;
  const int ldB0 = 16384 + wid * 1024;
  const int ldB1 = 24576 + wid * 1024;

  // ---- ds_read per-lane constants (swizzled) ----
  const int fr = lane & 15;
  const int fq = lane >> 4;
  const int wr = wid >> 2;    // 0..1 (rows)
  const int wc = wid & 3;     // 0..3 (cols)
  const int frh = fr >> 1;
  const int clA = (((fr & 1) << 2) | fq) ^ frh;
  const int aconst = wr * 8192 + frh * 128 + clA * 16;
  const int bconst = 16384 + wc * 4096 + frh * 128 + clA * 16;

  f32x4 acc[8][4] = {};

  // ---- prologue: stage tiles 0,1,2 into bufs 0,1,2 ----
#pragma unroll
  for (int tt = 0; tt < 3; ++tt) {
    char* lb = smem + tt * 32768;
    gload_lds16(srcA0 + tt * 32, lb + ldA0);
    gload_lds16(srcA1 + tt * 32, lb + ldA1);
    gload_lds16(srcB0 + tt * 32, lb + ldB0);
    gload_lds16(srcB1 + tt * 32, lb + ldB1);
  }

#define TILE_BODY(T, VMSTR, STAGE_)                                          \
  do {                                                                       \
    const char* rb = smem + ((T) & 3) * 32768;                               \
    char* lb = smem + (((T) + 3) & 3) * 32768;                               \
    if (STAGE_) {                                                            \
      gload_lds16(srcA0 + (size_t)((T) + 3) * 32, lb + ldA0);                \
      gload_lds16(srcA1 + (size_t)((T) + 3) * 32, lb + ldA1);                \
    }                                                                        \
    asm volatile("s_waitcnt vmcnt(" VMSTR ")" ::: "memory");                 \
    __builtin_amdgcn_s_barrier();                                            \
    short8 bf_[4], af[4];                                                    \
    _Pragma("unroll")                                                        \
    for (int ni = 0; ni < 4; ++ni)                                           \
      bf_[ni] = *(const short8*)(rb + bconst + ni * 1024);                   \
    _Pragma("unroll")                                                        \
    for (int mi = 0; mi < 4; ++mi)                                           \
      af[mi] = *(const short8*)(rb + aconst + mi * 1024);                    \
    __builtin_amdgcn_s_setprio(1);                                           \
    _Pragma("unroll")                                                        \
    for (int mi = 0; mi < 4; ++mi)                                           \
      _Pragma("unroll")                                                      \
      for (int ni = 0; ni < 4; ++ni)                                         \
        acc[mi][ni] = __builtin_amdgcn_mfma_f32_16x16x32_bf16(               \
            af[mi], bf_[ni], acc[mi][ni], 0, 0, 0);                          \
    __builtin_amdgcn_s_setprio(0);                                           \
    if (STAGE_) {                                                            \
      gload_lds16(srcB0 + (size_t)((T) + 3) * 32, lb + ldB0);                \
      gload_lds16(srcB1 + (size_t)((T) + 3) * 32, lb + ldB1);                \
    }                                                                        \
    short8 ag[4];                                                            \
    _Pragma("unroll")                                                        \
    for (int mi = 0; mi < 4; ++mi)                                           \
      ag[mi] = *(const short8*)(rb + aconst + (mi + 4) * 1024);              \
    __builtin_amdgcn_s_setprio(1);                                           \
    _Pragma("unroll")                                                        \
    for (int mi = 0; mi < 4; ++mi)                                           \
      _Pragma("unroll")                                                      \
      for (int ni = 0; ni < 4; ++ni)                                         \
        acc[mi + 4][ni] = __builtin_amdgcn_mfma_f32_16x16x32_bf16(           \
            ag[mi], bf_[ni], acc[mi + 4][ni], 0, 0, 0);                      \
    __builtin_amdgcn_s_setprio(0);                                           \
    asm volatile("s_waitcnt lgkmcnt(0)" ::: "memory");                       \
    __builtin_amdgcn_s_barrier();                                            \
  } while (0)

  for (int t = 0; t < NKT - 3; ++t) TILE_BODY(t, "10", true);
  TILE_BODY(NKT - 3, "8", false);
  TILE_BODY(NKT - 2, "4", false);
  TILE_BODY(NKT - 1, "0", false);
#undef TILE_BODY

  // ---- fused LSTM epilogue ----
  // Wave owns 128x64 gates: rows tm*256+wr*128+mi*16+[0,16), cols 16 j's x 4 gates.
  // Wave-private 4KiB LDS bounce (bytes wid*4096, inside bufs 0-1: all ring
  // reads retired before the final barrier above).
  const int jw = fr;
  const int jg = tn * 64 + wc * 16 + jw;   // global j in [0,2048)
  const f32x4 bi = *(const f32x4*)(bias + tn * 256 + wc * 64 + jw * 4);
  float* ep = (float*)smem + wid * 1024;

#pragma unroll
  for (int mi = 0; mi < 8; ++mi) {
#pragma unroll
    for (int ni = 0; ni < 4; ++ni)
#pragma unroll
      for (int r = 0; r < 4; ++r)
        ep[(fq * 4 + r) * 64 + ni * 16 + fr] = acc[mi][ni][r];
    asm volatile("s_waitcnt lgkmcnt(0)" ::: "memory");
#pragma unroll
    for (int t4 = 0; t4 < 4; ++t4) {
      const int row = fq + t4 * 4;         // 0..15
      f32x4 g4 = *(const f32x4*)(ep + row * 64 + jw * 4);
      const float f_in = g4[0] + bi[0];
      const float i_in = g4[1] + bi[1];
      const float ic_in = g4[2] + bi[2];
      const float o_in = g4[3] + bi[3];
      const float ft = sigmoidf_(f_in);
      const float it = sigmoidf_(i_in);
      const float ics = __sinf(ic_in);
      const int mg = tm * 256 + wr * 128 + mi * 16 + row;
      const float cv = c[(size_t)mg * HDIM + jg];
      const float ct = cv * ft + ics * it;
      const float ot = sigmoidf_(o_in);
      const float ht = ot * __sinf(ct);
      out[(size_t)mg * HDIM + jg] = ht;
      out[OUT_HALF + (size_t)mg * HDIM + jg] = ct;
    }
    asm volatile("s_waitcnt lgkmcnt(0)" ::: "memory");
  }
}

extern "C" void kernel_launch(void* const* d_in, const int* in_sizes, int n_in,
                              void* d_out, int out_size, void* d_ws, size_t ws_size,
                              hipStream_t stream) {
  const float* x    = (const float*)d_in[0];
  const float* h    = (const float*)d_in[1];
  const float* c    = (const float*)d_in[2];
  const float* w_ih = (const float*)d_in[3];
  const float* w_hh = (const float*)d_in[4];
  const float* b_ih = (const float*)d_in[5];
  const float* b_hh = (const float*)d_in[6];
  float* out = (float*)d_out;

  char* ws = (char*)d_ws;
  unsigned short* Abf = (unsigned short*)ws;                       // 25,165,824 B
  unsigned short* Wbf = (unsigned short*)(ws + 25165824);          // 50,331,648 B
  float* bias = (float*)(ws + 25165824 + 50331648);                // 32,768 B

  static_assert(sizeof(void*) == 8, "");
  hipFuncSetAttribute((const void*)lstm_gemm,
                      hipFuncAttributeMaxDynamicSharedMemorySize, 131072);

  pack_a<<<6144, 256, 0, stream>>>(x, h, Abf);
  pack_w<<<12288, 256, 0, stream>>>(w_ih, w_hh, b_ih, b_hh, Wbf, bias);
  lstm_gemm<<<512, 512, 131072, stream>>>(Abf, Wbf, bias, c, out);
}

// Round 4
// 222.629 us; speedup vs baseline: 1.6919x; 1.0486x over previous
//
#include <hip/hip_runtime.h>

typedef __attribute__((ext_vector_type(8))) short short8;
typedef __attribute__((ext_vector_type(4))) float f32x4;

// Problem dims
#define BDIM 4096
#define INDIM 1024
#define HDIM 2048
#define KDIM 3072   // IN + H
#define NDIM 8192   // 4*H
#define OUT_HALF 8388608  // 4096*2048
#define NKT 96      // K-tiles of 32

__device__ __forceinline__ unsigned short f2bf(float f) {
  unsigned u = __float_as_uint(f);
  u += 0x7FFFu + ((u >> 16) & 1u);
  return (unsigned short)(u >> 16);
}

__device__ __forceinline__ float sigmoidf_(float x) {
  return 1.0f / (1.0f + __expf(-x));
}

// Pack A = [x | h] as bf16, row-major [4096][3072]
__global__ __launch_bounds__(256) void pack_a(const float* __restrict__ x,
                                              const float* __restrict__ hh,
                                              unsigned short* __restrict__ A) {
  int idx = blockIdx.x * 256 + threadIdx.x;
  int m = idx / 384;
  int k0 = (idx - m * 384) * 8;
  const float* src = (k0 < INDIM) ? (x + (size_t)m * INDIM + k0)
                                  : (hh + (size_t)m * HDIM + (k0 - INDIM));
  float4 lo = ((const float4*)src)[0];
  float4 hi = ((const float4*)src)[1];
  union { unsigned short us[8]; uint4 v; } o;
  o.us[0] = f2bf(lo.x); o.us[1] = f2bf(lo.y); o.us[2] = f2bf(lo.z); o.us[3] = f2bf(lo.w);
  o.us[4] = f2bf(hi.x); o.us[5] = f2bf(hi.y); o.us[6] = f2bf(hi.z); o.us[7] = f2bf(hi.w);
  *(uint4*)(A + (size_t)m * KDIM + k0) = o.v;
}

// Pack W' (gate-interleaved rows) as bf16 [8192][3072]; W'[4*j+g] = [w_ih|w_hh][g*2048+j]
__global__ __launch_bounds__(256) void pack_w(const float* __restrict__ w_ih,
                                              const float* __restrict__ w_hh,
                                              const float* __restrict__ b_ih,
                                              const float* __restrict__ b_hh,
                                              unsigned short* __restrict__ W,
                                              float* __restrict__ bias) {
  int idx = blockIdx.x * 256 + threadIdx.x;
  int np = idx / 384;
  int rem = idx - np * 384;
  int k0 = rem * 8;
  int j = np >> 2;
  int g = np & 3;
  int n = g * HDIM + j;
  const float* src = (k0 < INDIM) ? (w_ih + (size_t)n * INDIM + k0)
                                  : (w_hh + (size_t)n * HDIM + (k0 - INDIM));
  float4 lo = ((const float4*)src)[0];
  float4 hi = ((const float4*)src)[1];
  union { unsigned short us[8]; uint4 v; } o;
  o.us[0] = f2bf(lo.x); o.us[1] = f2bf(lo.y); o.us[2] = f2bf(lo.z); o.us[3] = f2bf(lo.w);
  o.us[4] = f2bf(hi.x); o.us[5] = f2bf(hi.y); o.us[6] = f2bf(hi.z); o.us[7] = f2bf(hi.w);
  *(uint4*)(W + (size_t)np * KDIM + k0) = o.v;
  if (rem == 0) bias[np] = b_ih[n] + b_hh[n];
}

__device__ __forceinline__ void gload_lds16(const void* g, void* l) {
  __builtin_amdgcn_global_load_lds(
      (const __attribute__((address_space(1))) void*)g,
      (__attribute__((address_space(3))) void*)l, 16, 0, 0);
}

#define SB0 __builtin_amdgcn_sched_barrier(0)

// 256x256 tile, BK=32, 8 waves (2Mx4N), 4-deep LDS ring (4 x 32KiB),
// row-pair XOR swizzle (T2), counted vmcnt (T4), setprio (T5),
// software-pipelined ds_reads (T3): one barrier per K-tile; next-tile
// af reads issued before MFMA-B (which has zero memory dependency).
__global__ __launch_bounds__(512, 2) void lstm_gemm(
    const unsigned short* __restrict__ A,
    const unsigned short* __restrict__ W,
    const float* __restrict__ bias,
    const float* __restrict__ c,
    float* __restrict__ out) {
  extern __shared__ char smem[];  // 131072 bytes

  const int tid = threadIdx.x;
  const int lane = tid & 63;
  const int wid = tid >> 6;

  // XCD swizzle: xcd owns 2 tm slabs; tn sweeps slowest. Bijective over 512.
  const int bid = blockIdx.x;
  const int local = bid >> 3;
  const int tm = (bid & 7) * 2 + (local & 1);   // 0..15
  const int tn = local >> 1;                    // 0..31

  // ---- staging source decode (inverse swizzle, rule #21) ----
  int rowA0, clA0, rowA1, clA1;
  {
    int P0 = wid * 1024 + lane * 16;
    int P1 = 8192 + wid * 1024 + lane * 16;
    int r2, cp, cg;
    r2 = P0 >> 7; cp = (P0 >> 4) & 7; cg = cp ^ (r2 & 7);
    rowA0 = r2 * 2 + (cg >> 2); clA0 = cg & 3;
    r2 = P1 >> 7; cp = (P1 >> 4) & 7; cg = cp ^ (r2 & 7);
    rowA1 = r2 * 2 + (cg >> 2); clA1 = cg & 3;
  }
  const unsigned short* srcA0 = A + (size_t)(tm * 256 + rowA0) * KDIM + clA0 * 8;
  const unsigned short* srcA1 = A + (size_t)(tm * 256 + rowA1) * KDIM + clA1 * 8;
  const unsigned short* srcB0 = W + (size_t)(tn * 256 + rowA0) * KDIM + clA0 * 8;
  const unsigned short* srcB1 = W + (size_t)(tn * 256 + rowA1) * KDIM + clA1 * 8;
  const int ldA0 = wid * 1024;
  const int ldA1 = 8192 + wid * 1024;
  const int ldB0 = 16384 + wid * 1024;
  const int ldB1 = 24576 + wid * 1024;

  // ---- ds_read per-lane constants (swizzled) ----
  const int fr = lane & 15;
  const int fq = lane >> 4;
  const int wr = wid >> 2;    // 0..1 (rows)
  const int wc = wid & 3;     // 0..3 (cols)
  const int frh = fr >> 1;
  const int clA = (((fr & 1) << 2) | fq) ^ frh;
  const int aconst = wr * 8192 + frh * 128 + clA * 16;
  const int bconst = 16384 + wc * 4096 + frh * 128 + clA * 16;

  f32x4 acc[8][4] = {};
  short8 af[4], bf_[4], ag[4];

  // ---- prologue: stage tiles 0,1,2 ----
#pragma unroll
  for (int tt = 0; tt < 3; ++tt) {
    char* lb = smem + tt * 32768;
    gload_lds16(srcA0 + tt * 32, lb + ldA0);
    gload_lds16(srcA1 + tt * 32, lb + ldA1);
    gload_lds16(srcB0 + tt * 32, lb + ldB0);
    gload_lds16(srcB1 + tt * 32, lb + ldB1);
  }
  asm volatile("s_waitcnt vmcnt(8)" ::: "memory");   // tile 0 landed
  __builtin_amdgcn_s_barrier(); SB0;
  // issue af(0), bf_(0)
#pragma unroll
  for (int mi = 0; mi < 4; ++mi)
    af[mi] = *(const short8*)(smem + aconst + mi * 1024);
#pragma unroll
  for (int ni = 0; ni < 4; ++ni)
    bf_[ni] = *(const short8*)(smem + bconst + ni * 1024);

// Tile body. Entry: af(T),bf_(T) issued; vm queue = stages for T+1,T+2 (8).
#define TILE_BODY(T, VMSTR, STAGE_, PREF_)                                   \
  do {                                                                       \
    const char* rb = smem + ((T) & 3) * 32768;                               \
    const char* rbn = smem + (((T) + 1) & 3) * 32768;                        \
    char* lb = smem + (((T) + 3) & 3) * 32768;                               \
    if (STAGE_) {                                                            \
      gload_lds16(srcA0 + (size_t)((T) + 3) * 32, lb + ldA0);                \
      gload_lds16(srcA1 + (size_t)((T) + 3) * 32, lb + ldA1);                \
    }                                                                        \
    _Pragma("unroll")                                                        \
    for (int mi = 0; mi < 4; ++mi)                                           \
      ag[mi] = *(const short8*)(rb + aconst + (mi + 4) * 1024);              \
    SB0;                                                                     \
    __builtin_amdgcn_s_setprio(1);                                           \
    _Pragma("unroll")                                                        \
    for (int mi = 0; mi < 4; ++mi)                                           \
      _Pragma("unroll")                                                      \
      for (int ni = 0; ni < 4; ++ni)                                         \
        acc[mi][ni] = __builtin_amdgcn_mfma_f32_16x16x32_bf16(               \
            af[mi], bf_[ni], acc[mi][ni], 0, 0, 0);                          \
    __builtin_amdgcn_s_setprio(0);                                           \
    if (STAGE_) {                                                            \
      gload_lds16(srcB0 + (size_t)((T) + 3) * 32, lb + ldB0);                \
      gload_lds16(srcB1 + (size_t)((T) + 3) * 32, lb + ldB1);                \
    }                                                                        \
    asm volatile("s_waitcnt vmcnt(" VMSTR ")" ::: "memory");                 \
    asm volatile("s_waitcnt lgkmcnt(0)" ::: "memory");                       \
    __builtin_amdgcn_s_barrier(); SB0;                                       \
    if (PREF_) {                                                             \
      _Pragma("unroll")                                                      \
      for (int mi = 0; mi < 4; ++mi)                                         \
        af[mi] = *(const short8*)(rbn + aconst + mi * 1024);                 \
    }                                                                        \
    SB0;                                                                     \
    __builtin_amdgcn_s_setprio(1);                                           \
    _Pragma("unroll")                                                        \
    for (int mi = 0; mi < 4; ++mi)                                           \
      _Pragma("unroll")                                                      \
      for (int ni = 0; ni < 4; ++ni)                                         \
        acc[mi + 4][ni] = __builtin_amdgcn_mfma_f32_16x16x32_bf16(           \
            ag[mi], bf_[ni], acc[mi + 4][ni], 0, 0, 0);                      \
    __builtin_amdgcn_s_setprio(0);                                           \
    if (PREF_) {                                                             \
      _Pragma("unroll")                                                      \
      for (int ni = 0; ni < 4; ++ni)                                         \
        bf_[ni] = *(const short8*)(rbn + bconst + ni * 1024);                \
    }                                                                        \
  } while (0)

  for (int t = 0; t < NKT - 3; ++t) TILE_BODY(t, "8", true, true);
  TILE_BODY(NKT - 3, "4", false, true);
  TILE_BODY(NKT - 2, "0", false, true);
  TILE_BODY(NKT - 1, "0", false, false);
#undef TILE_BODY

  // ---- fused LSTM epilogue ----
  // Wave-private 4KiB LDS bounce at bytes wid*4096 (all ring reads retired).
  const int jw = fr;
  const int jg = tn * 64 + wc * 16 + jw;   // global j in [0,2048)
  const f32x4 bi = *(const f32x4*)(bias + tn * 256 + wc * 64 + jw * 4);
  float* ep = (float*)smem + wid * 1024;

#pragma unroll
  for (int mi = 0; mi < 8; ++mi) {
#pragma unroll
    for (int ni = 0; ni < 4; ++ni)
#pragma unroll
      for (int r = 0; r < 4; ++r)
        ep[(fq * 4 + r) * 64 + ni * 16 + fr] = acc[mi][ni][r];
    asm volatile("s_waitcnt lgkmcnt(0)" ::: "memory");
#pragma unroll
    for (int t4 = 0; t4 < 4; ++t4) {
      const int row = fq + t4 * 4;         // 0..15
      f32x4 g4 = *(const f32x4*)(ep + row * 64 + jw * 4);
      const float f_in = g4[0] + bi[0];
      const float i_in = g4[1] + bi[1];
      const float ic_in = g4[2] + bi[2];
      const float o_in = g4[3] + bi[3];
      const float ft = sigmoidf_(f_in);
      const float it = sigmoidf_(i_in);
      const float ics = __sinf(ic_in);
      const int mg = tm * 256 + wr * 128 + mi * 16 + row;
      const float cv = c[(size_t)mg * HDIM + jg];
      const float ct = cv * ft + ics * it;
      const float ot = sigmoidf_(o_in);
      const float ht = ot * __sinf(ct);
      out[(size_t)mg * HDIM + jg] = ht;
      out[OUT_HALF + (size_t)mg * HDIM + jg] = ct;
    }
    asm volatile("s_waitcnt lgkmcnt(0)" ::: "memory");
  }
}

extern "C" void kernel_launch(void* const* d_in, const int* in_sizes, int n_in,
                              void* d_out, int out_size, void* d_ws, size_t ws_size,
                              hipStream_t stream) {
  const float* x    = (const float*)d_in[0];
  const float* h    = (const float*)d_in[1];
  const float* c    = (const float*)d_in[2];
  const float* w_ih = (const float*)d_in[3];
  const float* w_hh = (const float*)d_in[4];
  const float* b_ih = (const float*)d_in[5];
  const float* b_hh = (const float*)d_in[6];
  float* out = (float*)d_out;

  char* ws = (char*)d_ws;
  unsigned short* Abf = (unsigned short*)ws;                       // 25,165,824 B
  unsigned short* Wbf = (unsigned short*)(ws + 25165824);          // 50,331,648 B
  float* bias = (float*)(ws + 25165824 + 50331648);                // 32,768 B

  hipFuncSetAttribute((const void*)lstm_gemm,
                      hipFuncAttributeMaxDynamicSharedMemorySize, 131072);

  pack_a<<<6144, 256, 0, stream>>>(x, h, Abf);
  pack_w<<<12288, 256, 0, stream>>>(w_ih, w_hh, b_ih, b_hh, Wbf, bias);
  lstm_gemm<<<512, 512, 131072, stream>>>(Abf, Wbf, bias, c, out);
}